// Round 18
// baseline (339.737 us; speedup 1.0000x reference)
//
#include <hip/hip_runtime.h>
#include <hip/hip_bf16.h>

#define NNODE 10000
#define NEDGE 160000
#define HIDD  256
#define ED    128
#define CAT   640

typedef short bf8 __attribute__((ext_vector_type(8)));
typedef short bf4 __attribute__((ext_vector_type(4)));
typedef float f4  __attribute__((ext_vector_type(4)));
typedef unsigned int u32;

__device__ __forceinline__ float bf2f(ushort u) {
    return __uint_as_float(((unsigned)u) << 16);
}
__device__ __forceinline__ ushort f2bf(float f) {
    unsigned u = __float_as_uint(f);
    return (ushort)((u + 0x7fffu + ((u >> 16) & 1u)) >> 16);
}
__device__ __forceinline__ float gelu_fast(float x) {
    float x2 = x * x;
    float u = 0.7978845608028654f * x * (1.0f + 0.044715f * x2);
    float au = fabsf(u);
    float ex = __expf(2.0f * au);
    float t = 1.0f - 2.0f / (1.0f + ex);
    t = copysignf(t, u);
    return 0.5f * x * (1.0f + t);
}
__device__ __forceinline__ int clampi(int v) {
    return ((unsigned)v >= (unsigned)NNODE) ? 0 : v;
}
__device__ __forceinline__ int getidx(const int* ei, bool i64, int pos) {
    int v = i64 ? ei[2 * pos] : ei[pos];
    return clampi(v);
}
__device__ __forceinline__ float loadf(const void* p, size_t idx, bool f32) {
    return f32 ? ((const float*)p)[idx] : bf2f(((const ushort*)p)[idx]);
}
__device__ __forceinline__ bf8 load8(const void* p, size_t idx, bool f32) {
    if (f32) {
        const float* fp = (const float*)p + idx;
        f4 lo = *(const f4*)fp, hi = *(const f4*)(fp + 4);
        bf8 r;
        r[0] = (short)f2bf(lo[0]); r[1] = (short)f2bf(lo[1]);
        r[2] = (short)f2bf(lo[2]); r[3] = (short)f2bf(lo[3]);
        r[4] = (short)f2bf(hi[0]); r[5] = (short)f2bf(hi[1]);
        r[6] = (short)f2bf(hi[2]); r[7] = (short)f2bf(hi[3]);
        return r;
    }
    return *(const bf8*)((const ushort*)p + idx);
}
__device__ __forceinline__ void storef(void* p, size_t idx, float v, bool f32) {
    if (f32) ((float*)p)[idx] = v;
    else     ((ushort*)p)[idx] = f2bf(v);
}
__device__ __forceinline__ void fadd_native(float* p, float v) {
    unsafeAtomicAdd(p, v);
}
__device__ __forceinline__ void detect_local(const u32* h_u32, const u32* ei_u32,
                                             u32* sf) {
    if (threadIdx.x < 64) {
        int t = threadIdx.x;
        u32 e8 = (h_u32[t] >> 7) & 0xFFu;
        bool inw = (e8 >= 100u && e8 <= 150u);
        unsigned long long m = __ballot(inw);
        bool hi_nz = (t < 16) ? (ei_u32[2 * t + 1] != 0u) : false;
        unsigned long long m2 = __ballot(hi_nz);
        if (t == 0) {
            sf[0] = (__popcll(m) < 40) ? 1u : 0u;
            sf[1] = (m2 == 0ull) ? 1u : 0u;
        }
    }
    __syncthreads();
}

// ============ combo: prep (1280) + count (625) + S-zero (2500) ============
#define PREP_B 1280
#define COUNT_B 625
#define SZERO_B 2500
__global__ __launch_bounds__(256) void combo_kernel(
    const void* __restrict__ h, const int* __restrict__ ei,
    const void* __restrict__ We1, const void* __restrict__ We2,
    const void* __restrict__ Wv1, const void* __restrict__ Wv2,
    ushort* __restrict__ WT, float* __restrict__ S,
    u32* __restrict__ cnt, u32* __restrict__ flags)
{
    __shared__ u32 sf[2];
    detect_local((const u32*)h, (const u32*)ei, sf);
    const bool f32 = sf[0] != 0, i64 = sf[1] != 0;
    int b = blockIdx.x, tid = threadIdx.x;

    if (b == 0 && tid == 0) { flags[0] = sf[0]; flags[1] = sf[1]; }

    if (b < PREP_B) {
        int idx = b * 256 + tid;
        if (idx >= 327680) return;
        const void* W; int base, k0, K, Wld;
        if      (idx <  32768) { W = We1; base = 0;      k0 = 0;   K = 256; Wld = 128; }
        else if (idx <  65536) { W = We1; base = 32768;  k0 = 256; K = 256; Wld = 128; }
        else if (idx <  81920) { W = We1; base = 65536;  k0 = 512; K = 128; Wld = 128; }
        else if (idx <  98304) { W = We2; base = 81920;  k0 = 0;   K = 128; Wld = 128; }
        else if (idx < 163840) { W = Wv1; base = 98304;  k0 = 0;   K = 256; Wld = 256; }
        else if (idx < 229376) { W = Wv1; base = 163840; k0 = 256; K = 256; Wld = 256; }
        else if (idx < 262144) { W = Wv1; base = 229376; k0 = 512; K = 128; Wld = 256; }
        else                   { W = Wv2; base = 262144; k0 = 0;   K = 256; Wld = 256; }
        int local = idx - base;
        int k = local & (K - 1);
        int n = local / K;
        WT[idx] = f2bf(loadf(W, (size_t)(k0 + k) * Wld + n, f32));
    } else if (b < PREP_B + COUNT_B) {
        int i = (b - PREP_B) * 256 + tid;
        if (i < NEDGE) atomicAdd(&cnt[getidx(ei, i64, NEDGE + i)], 1u);
    } else {
        size_t i = (size_t)(b - PREP_B - COUNT_B) * 256 + tid;   // f4 slots
        if (i < (size_t)NNODE * HIDD / 4) {
            f4 z = {};
            *(f4*)&S[i * 4] = z;
        }
    }
}

// ---- exclusive prefix scan over cnt -> head ----
__global__ void scan_kernel(const u32* __restrict__ cnt, int* __restrict__ head) {
    __shared__ u32 part[256];
    __shared__ u32 base[256];
    int t = threadIdx.x;
    u32 s = 0;
    for (int j = 0; j < 40; ++j) {
        int i = t * 40 + j;
        if (i < NNODE) s += cnt[i];
    }
    part[t] = s;
    __syncthreads();
    if (t == 0) {
        u32 run = 0;
        for (int i = 0; i < 256; ++i) { base[i] = run; run += part[i]; }
    }
    __syncthreads();
    u32 run = base[t];
    for (int j = 0; j < 40; ++j) {
        int i = t * 40 + j;
        if (i < NNODE) { head[i] = (int)run; run += cnt[i]; }
    }
}

// ---- node-level projections from RAW h, permuted store + bias folding ----
template<int NB>
__device__ __forceinline__ void qp_body(const void* __restrict__ h,
                                        const ushort* __restrict__ WT,
                                        const void* __restrict__ bias,
                                        ushort* __restrict__ O, int bid, bool f32) {
    const int tid = threadIdx.x;
    const int wid = tid >> 6, lane = tid & 63;
    const int l16 = lane & 15, lg = lane >> 4;
    const int node0 = bid * 64;
    const int N = NB * 64;
    const int n0 = wid * (NB * 16);

    size_t ra[4];
    #pragma unroll
    for (int ai = 0; ai < 4; ++ai) {
        int row = node0 + ai * 16 + l16;
        ra[ai] = (size_t)(row < NNODE ? row : NNODE - 1) * HIDD;
    }
    int bb[NB];
    #pragma unroll
    for (int bi = 0; bi < NB; ++bi) bb[bi] = (n0 + bi * 16 + l16) * HIDD;

    f4 acc[4][NB] = {};
    for (int kc = 0; kc < 4; ++kc) {
        #pragma unroll
        for (int ks = 0; ks < 2; ++ks) {
            int kk = kc * 64 + ks * 32 + lg * 8;
            bf8 b[NB];
            #pragma unroll
            for (int bi = 0; bi < NB; ++bi) b[bi] = *(const bf8*)&WT[bb[bi] + kk];
            #pragma unroll
            for (int ai = 0; ai < 4; ++ai) {
                bf8 a = load8(h, ra[ai] + kk, f32);
                #pragma unroll
                for (int bi = 0; bi < NB; ++bi)
                    acc[ai][bi] = __builtin_amdgcn_mfma_f32_16x16x32_bf16(a, b[bi], acc[ai][bi], 0, 0, 0);
            }
        }
    }
    #pragma unroll
    for (int bi = 0; bi < NB; ++bi) {
        int col = n0 + bi * 16 + l16;
        int pcol; float badd;
        if constexpr (NB == 4) {
            int hh = col >> 7, c = col & 127;
            badd = (hh == 0) ? loadf(bias, c, f32) : 0.f;
            pcol = hh * 128 + (c & 15) * 8 + (c >> 4);
        } else {
            int hh = col >> 8, c = col & 255;
            badd = (hh == 0) ? loadf(bias, c, f32) : 0.f;
            int nh2 = c >> 7, rem = c & 127, w = rem >> 5, b2 = (rem >> 4) & 1, l = c & 15;
            pcol = hh * 256 + w * 64 + l * 4 + nh2 * 2 + b2;
        }
        #pragma unroll
        for (int ai = 0; ai < 4; ++ai)
            #pragma unroll
            for (int r = 0; r < 4; ++r) {
                int gr = node0 + ai * 16 + lg * 4 + r;
                if (gr < NNODE) O[(size_t)gr * N + pcol] = f2bf(acc[ai][bi][r] + badd);
            }
    }
}

// ============ fill (625) + qp2 merged ============
#define QPB ((NNODE + 63) / 64)
#define FILL_B 625
__global__ __launch_bounds__(256) void fillqp_kernel(
    const int* __restrict__ ei, int* __restrict__ head,
    int* __restrict__ perm, int* __restrict__ dsts,
    const void* __restrict__ h, const ushort* __restrict__ WTe,
    const ushort* __restrict__ WTv, const void* __restrict__ be1,
    const void* __restrict__ bv1, ushort* __restrict__ Qab,
    ushort* __restrict__ Pab, const u32* __restrict__ flags)
{
    const bool f32 = flags[0] != 0, i64 = flags[1] != 0;
    int b = blockIdx.x;
    if (b < FILL_B) {
        int i = b * 256 + threadIdx.x;
        if (i < NEDGE) {
            int d = getidx(ei, i64, NEDGE + i);
            int pos = atomicAdd(&head[d], 1);
            perm[pos] = i;
            dsts[pos] = d;
        }
    } else if (b < FILL_B + QPB) {
        qp_body<4>(h, WTe, be1, Qab, b - FILL_B, f32);
    } else {
        qp_body<8>(h, WTv, bv1, Pab, b - FILL_B - QPB, f32);
    }
}

// ============ FUSED edge+node1 (dst-sorted), 64 edges/block, 256 thr ============
#define FWG (NEDGE / 64)   // 2500 blocks
__global__ __launch_bounds__(256) void fused_kernel(
    const void* __restrict__ e, const int* __restrict__ ei,
    const int* __restrict__ perm, const int* __restrict__ dsts,
    const ushort* __restrict__ WT1c,
    const ushort* __restrict__ WT2, const void* __restrict__ be2,
    const ushort* __restrict__ Qab,
    const void* __restrict__ neg, const void* __restrict__ neb,
    const ushort* __restrict__ WvcT,
    const ushort* __restrict__ Pab,
    float* __restrict__ S, void* __restrict__ out,
    const u32* __restrict__ flags)
{
    const bool f32 = flags[0] != 0, i64 = flags[1] != 0;
    __shared__ ushort Asm[64 * 136];
    __shared__ ushort Bsm[128 * 136];
    __shared__ ushort Tsm[64 * 136];
    __shared__ int PermS[64], SrcS[64], DstS[64];

    int orig = blockIdx.x;
    int xcd = orig & 7, slot = orig >> 3;
    int bid = (xcd < 4 ? xcd * 313 : 4 * 313 + (xcd - 4) * 312) + slot;

    const int tid = threadIdx.x;
    const int wid = tid >> 6, lane = tid & 63;
    const int l16 = lane & 15, lg = lane >> 4;
    const int edge0 = bid * 64;
    const int rm = wid * 16;

    if (tid < 64) {
        int eid = perm[edge0 + tid];
        PermS[tid] = eid;
        SrcS[tid] = getidx(ei, i64, eid);
        DstS[tid] = dsts[edge0 + tid];
    }
    __syncthreads();

    // ---- stage A (e rows, full width, once) + B for phase 1 ----
    #pragma unroll
    for (int j = 0; j < 4; ++j) {
        int s2 = tid + j * 256;
        int r = s2 >> 4, c8 = (s2 & 15) * 8;
        *(bf8*)&Asm[r * 136 + c8] = load8(e, (size_t)PermS[r] * ED + c8, f32);
    }
    #pragma unroll
    for (int it = 0; it < 8; ++it) {
        int s2 = tid + it * 256;
        int n = s2 >> 4, c8 = (s2 & 15) * 8;
        *(bf8*)&Bsm[n * 136 + c8] = *(const bf8*)&WT1c[n * 128 + c8];
    }
    __syncthreads();

    // ---------- phase 1: T1 = e @ WT1c^T (K=128) ----------
    f4 acc[8] = {};
    #pragma unroll
    for (int kc = 0; kc < 2; ++kc)
        #pragma unroll
        for (int ks = 0; ks < 2; ++ks) {
            int ko = kc * 64 + ks * 32 + lg * 8;
            bf8 a = *(const bf8*)&Asm[(rm + l16) * 136 + ko];
            #pragma unroll
            for (int f = 0; f < 8; ++f) {
                bf8 b = *(const bf8*)&Bsm[(f * 16 + l16) * 136 + ko];
                acc[f] = __builtin_amdgcn_mfma_f32_16x16x32_bf16(a, b, acc[f], 0, 0, 0);
            }
        }

    // epilogue 1: + (be1 in Qab) + Qa[src] + Qb[dst], gelu -> Tsm
    {
        bf8 qs[4], qd[4];
        #pragma unroll
        for (int r = 0; r < 4; ++r) {
            int row = rm + lg * 4 + r;
            qs[r] = *(const bf8*)&Qab[(size_t)SrcS[row] * 256 + l16 * 8];
            qd[r] = *(const bf8*)&Qab[(size_t)DstS[row] * 256 + 128 + l16 * 8];
        }
        #pragma unroll
        for (int f = 0; f < 8; ++f)
            #pragma unroll
            for (int r = 0; r < 4; ++r) {
                float val = acc[f][r] + bf2f((ushort)qs[r][f]) + bf2f((ushort)qd[r][f]);
                Tsm[(rm + lg * 4 + r) * 136 + f * 16 + l16] = f2bf(gelu_fast(val));
            }
    }
    __syncthreads();   // protect Bsm overwrite

    // ---- stage B for phase 2 ----
    #pragma unroll
    for (int it = 0; it < 8; ++it) {
        int s2 = tid + it * 256;
        int n = s2 >> 4, c8 = (s2 & 15) * 8;
        *(bf8*)&Bsm[n * 136 + c8] = *(const bf8*)&WT2[n * 128 + c8];
    }
    __syncthreads();

    // ---------- phase 2: T2 = T1 @ WT2^T (K=128) ----------
    f4 acc2[8] = {};
    #pragma unroll
    for (int kc = 0; kc < 2; ++kc)
        #pragma unroll
        for (int ks = 0; ks < 2; ++ks) {
            int ko = kc * 64 + ks * 32 + lg * 8;
            bf8 a = *(const bf8*)&Tsm[(rm + l16) * 136 + ko];
            #pragma unroll
            for (int f = 0; f < 8; ++f) {
                bf8 b = *(const bf8*)&Bsm[(f * 16 + l16) * 136 + ko];
                acc2[f] = __builtin_amdgcn_mfma_f32_16x16x32_bf16(a, b, acc2[f], 0, 0, 0);
            }
        }

    // epilogue 2: + be2 + e residual (from Asm), LN -> Tsm (bf16 e_new)
    {
        float v[8][4];
        #pragma unroll
        for (int f = 0; f < 8; ++f) {
            int col = f * 16 + l16;
            float bias = loadf(be2, col, f32);
            #pragma unroll
            for (int r = 0; r < 4; ++r) {
                int row = rm + lg * 4 + r;
                v[f][r] = acc2[f][r] + bias + bf2f(Asm[row * 136 + col]);
            }
        }
        #pragma unroll
        for (int r = 0; r < 4; ++r) {
            float s = 0.f;
            #pragma unroll
            for (int f = 0; f < 8; ++f) s += v[f][r];
            s += __shfl_xor(s, 1); s += __shfl_xor(s, 2);
            s += __shfl_xor(s, 4); s += __shfl_xor(s, 8);
            float mu = s * (1.0f / 128.0f);
            float q = 0.f;
            #pragma unroll
            for (int f = 0; f < 8; ++f) { float d = v[f][r] - mu; q += d * d; }
            q += __shfl_xor(q, 1); q += __shfl_xor(q, 2);
            q += __shfl_xor(q, 4); q += __shfl_xor(q, 8);
            float rstd = rsqrtf(q * (1.0f / 128.0f) + 1e-5f);
            int row = rm + lg * 4 + r;
            #pragma unroll
            for (int f = 0; f < 8; ++f) {
                int col = f * 16 + l16;
                float y = (v[f][r] - mu) * rstd * loadf(neg, col, f32) + loadf(neb, col, f32);
                Tsm[row * 136 + col] = f2bf(y);
            }
        }
    }
    __syncthreads();   // publish e_new cross-wave

    // ---- hoisted Pab gathers: hidden under e_new write + phase-3 MFMAs ----
    bf4 ps[4][4], pd[4][4];
    #pragma unroll
    for (int ai = 0; ai < 4; ++ai) {
        int p0 = ai * 16 + lg * 4;
        #pragma unroll
        for (int r = 0; r < 4; ++r) {
            ps[ai][r] = *(const bf4*)&Pab[(size_t)SrcS[p0 + r] * 512 + wid * 64 + l16 * 4];
            pd[ai][r] = *(const bf4*)&Pab[(size_t)DstS[p0 + r] * 512 + 256 + wid * 64 + l16 * 4];
        }
    }

    // ---- bulk e_new global write from Tsm ----
    {
        int row = tid >> 2, pc = (tid & 3) * 32;
        size_t obase = (size_t)NNODE * HIDD + (size_t)PermS[row] * ED + pc;
        #pragma unroll
        for (int q2 = 0; q2 < 4; ++q2) {
            bf8 w = *(const bf8*)&Tsm[row * 136 + pc + q2 * 8];
            if (f32) {
                f4 lo, hi;
                lo[0] = bf2f((ushort)w[0]); lo[1] = bf2f((ushort)w[1]);
                lo[2] = bf2f((ushort)w[2]); lo[3] = bf2f((ushort)w[3]);
                hi[0] = bf2f((ushort)w[4]); hi[1] = bf2f((ushort)w[5]);
                hi[2] = bf2f((ushort)w[6]); hi[3] = bf2f((ushort)w[7]);
                *(f4*)((float*)out + obase + q2 * 8) = lo;
                *(f4*)((float*)out + obase + q2 * 8 + 4) = hi;
            } else {
                *(bf8*)((ushort*)out + obase + q2 * 8) = w;
            }
        }
    }

    // ---------- phase 3: U = e_new @ WvcT^T, B DIRECT from global (L2-hot) ----------
    f4 accN[4][2][2] = {};
    #pragma unroll
    for (int nh = 0; nh < 2; ++nh)
        #pragma unroll
        for (int kc = 0; kc < 2; ++kc)
            #pragma unroll
            for (int ks = 0; ks < 2; ++ks) {
                int ko = kc * 64 + ks * 32 + lg * 8;
                bf8 a[4], b[2];
                #pragma unroll
                for (int bi = 0; bi < 2; ++bi)
                    b[bi] = *(const bf8*)&WvcT[(nh * 128 + wid * 32 + bi * 16 + l16) * 128 + ko];
                #pragma unroll
                for (int ai = 0; ai < 4; ++ai)
                    a[ai] = *(const bf8*)&Tsm[(ai * 16 + l16) * 136 + ko];
                #pragma unroll
                for (int ai = 0; ai < 4; ++ai)
                    #pragma unroll
                    for (int bi = 0; bi < 2; ++bi)
                        accN[ai][nh][bi] = __builtin_amdgcn_mfma_f32_16x16x32_bf16(a[ai], b[bi], accN[ai][nh][bi], 0, 0, 0);
            }

    // epilogue 3: + (bv1 in Pab) + Pa[src] + Pb[dst] (pre-gathered), merged scatter
    #pragma unroll
    for (int ai = 0; ai < 4; ++ai) {
        int p0 = ai * 16 + lg * 4;
        int dd[4];
        #pragma unroll
        for (int r = 0; r < 4; ++r) dd[r] = DstS[p0 + r];
        #pragma unroll
        for (int nh = 0; nh < 2; ++nh)
            #pragma unroll
            for (int bi = 0; bi < 2; ++bi) {
                int col = nh * 128 + wid * 32 + bi * 16 + l16;
                const int j = nh * 2 + bi;
                float v0 = gelu_fast(accN[ai][nh][bi][0] + bf2f((ushort)ps[ai][0][j]) + bf2f((ushort)pd[ai][0][j]));
                float v1 = gelu_fast(accN[ai][nh][bi][1] + bf2f((ushort)ps[ai][1][j]) + bf2f((ushort)pd[ai][1][j]));
                float v2 = gelu_fast(accN[ai][nh][bi][2] + bf2f((ushort)ps[ai][2][j]) + bf2f((ushort)pd[ai][2][j]));
                float v3 = gelu_fast(accN[ai][nh][bi][3] + bf2f((ushort)ps[ai][3][j]) + bf2f((ushort)pd[ai][3][j]));
                float s = v0; int d = dd[0];
                if (dd[1] == d) s += v1; else { fadd_native(&S[(size_t)d * HIDD + col], s); d = dd[1]; s = v1; }
                if (dd[2] == d) s += v2; else { fadd_native(&S[(size_t)d * HIDD + col], s); d = dd[2]; s = v2; }
                if (dd[3] == d) s += v3; else { fadd_native(&S[(size_t)d * HIDD + col], s); d = dd[3]; s = v3; }
                fadd_native(&S[(size_t)d * HIDD + col], s);
            }
    }
}

// ---- node phase 2 + LN ----
__global__ __launch_bounds__(256) void hn_gemm_kernel(
    const float* __restrict__ S, const ushort* __restrict__ WTv2,
    const void* __restrict__ bv2, const u32* __restrict__ cnt,
    const void* __restrict__ h,
    const void* __restrict__ nvg, const void* __restrict__ nvb,
    void* __restrict__ out, const u32* __restrict__ flags)
{
    const bool f32 = flags[0] != 0;
    constexpr int LDV = 260;
    __shared__ float Vsm[64 * LDV];

    const int tid = threadIdx.x;
    const int wid = tid >> 6, lane = tid & 63;
    const int l16 = lane & 15, lg = lane >> 4;
    const int node0 = blockIdx.x * 64;
    const int n0 = wid * 64;

    size_t ra[4];
    #pragma unroll
    for (int ai = 0; ai < 4; ++ai) {
        int row = node0 + ai * 16 + l16;
        ra[ai] = (size_t)(row < NNODE ? row : NNODE - 1) * HIDD;
    }
    int bb[4];
    #pragma unroll
    for (int bi = 0; bi < 4; ++bi) bb[bi] = (n0 + bi * 16 + l16) * HIDD;

    f4 acc[4][4] = {};
    for (int kc = 0; kc < 4; ++kc) {
        #pragma unroll
        for (int ks = 0; ks < 2; ++ks) {
            int kk = kc * 64 + ks * 32 + lg * 8;
            bf8 b[4];
            #pragma unroll
            for (int bi = 0; bi < 4; ++bi) b[bi] = *(const bf8*)&WTv2[bb[bi] + kk];
            #pragma unroll
            for (int ai = 0; ai < 4; ++ai) {
                bf8 a = load8(S, ra[ai] + kk, true);
                #pragma unroll
                for (int bi = 0; bi < 4; ++bi)
                    acc[ai][bi] = __builtin_amdgcn_mfma_f32_16x16x32_bf16(a, b[bi], acc[ai][bi], 0, 0, 0);
            }
        }
    }

    #pragma unroll
    for (int bi = 0; bi < 4; ++bi) {
        int col = n0 + bi * 16 + l16;
        float b2 = loadf(bv2, col, f32);
        #pragma unroll
        for (int ai = 0; ai < 4; ++ai)
            #pragma unroll
            for (int r = 0; r < 4; ++r) {
                int rowl = ai * 16 + lg * 4 + r;
                int gr = node0 + rowl;
                int grc = gr < NNODE ? gr : NNODE - 1;
                float c = (float)cnt[grc];
                float inv = 1.0f / fmaxf(c, 1.0f);
                float val = (acc[ai][bi][r] + c * b2) * inv
                          + loadf(h, (size_t)grc * HIDD + col, f32);
                Vsm[rowl * LDV + col] = val;
            }
    }
    __syncthreads();

    #pragma unroll
    for (int rr = 0; rr < 4; ++rr) {
        int rowl = wid * 16 + lg * 4 + rr;
        int gr = node0 + rowl;
        float x[16];
        #pragma unroll
        for (int f = 0; f < 16; ++f) x[f] = Vsm[rowl * LDV + f * 16 + l16];
        float s = 0.f;
        #pragma unroll
        for (int f = 0; f < 16; ++f) s += x[f];
        s += __shfl_xor(s, 1); s += __shfl_xor(s, 2);
        s += __shfl_xor(s, 4); s += __shfl_xor(s, 8);
        float mu = s * (1.0f / 256.0f);
        float q = 0.f;
        #pragma unroll
        for (int f = 0; f < 16; ++f) { float d = x[f] - mu; q += d * d; }
        q += __shfl_xor(q, 1); q += __shfl_xor(q, 2);
        q += __shfl_xor(q, 4); q += __shfl_xor(q, 8);
        float rstd = rsqrtf(q * (1.0f / 256.0f) + 1e-5f);
        if (gr < NNODE) {
            #pragma unroll
            for (int f = 0; f < 16; ++f) {
                int col = f * 16 + l16;
                float y = (x[f] - mu) * rstd * loadf(nvg, col, f32) + loadf(nvb, col, f32);
                storef(out, (size_t)gr * HIDD + col, y, f32);
            }
        }
    }
}

extern "C" void kernel_launch(void* const* d_in, const int* in_sizes, int n_in,
                              void* d_out, int out_size, void* d_ws, size_t ws_size,
                              hipStream_t stream)
{
    (void)in_sizes; (void)n_in; (void)out_size; (void)ws_size;
    const void* h   = d_in[0];
    const void* e   = d_in[1];
    const int*  ei  = (const int*)d_in[2];
    const void* We1 = d_in[3];
    const void* be1 = d_in[4];
    const void* We2 = d_in[5];
    const void* be2 = d_in[6];
    const void* Wv1 = d_in[7];
    const void* bv1 = d_in[8];
    const void* Wv2 = d_in[9];
    const void* bv2 = d_in[10];
    const void* neg = d_in[11];
    const void* neb = d_in[12];
    const void* nvg = d_in[13];
    const void* nvb = d_in[14];

    char* ws = (char*)d_ws;
    u32*   flags = (u32*)ws;
    float* S     = (float*)(ws + 256);
    u32*   cnt   = (u32*)(ws + 256 + (size_t)NNODE * HIDD * 4);
    size_t off = 256 + (size_t)NNODE * HIDD * 4 + ((size_t)NNODE * 4 + 255) / 256 * 256;
    int*   head = (int*)(ws + off);            off += ((size_t)NNODE * 4 + 255) / 256 * 256;
    int*   perm = (int*)(ws + off);            off += (size_t)NEDGE * 4;
    int*   dsts = (int*)(ws + off);            off += (size_t)NEDGE * 4;
    ushort* WTb  = (ushort*)(ws + off);
    ushort* WTe  = WTb;                        // [256][256]
    ushort* WT1c = WTb + 65536;                // [128][128]
    ushort* WT2  = WTb + 81920;                // [128][128]
    ushort* WTv  = WTb + 98304;                // [512][256]
    ushort* WvcT = WTb + 229376;               // [256][128]
    ushort* WTv2 = WTb + 262144;               // [256][256]
    ushort* Qab  = WTb + 327680;                       // [10000][256] bf16 (permuted)
    ushort* Pab  = Qab + (size_t)NNODE * 256;          // [10000][512] bf16 (permuted)

    hipMemsetAsync(cnt, 0, (size_t)NNODE * 4, stream);

    combo_kernel<<<PREP_B + COUNT_B + SZERO_B, 256, 0, stream>>>(
        h, ei, We1, We2, Wv1, Wv2, WTb, S, cnt, flags);
    scan_kernel<<<1, 256, 0, stream>>>(cnt, head);
    fillqp_kernel<<<FILL_B + 2 * QPB, 256, 0, stream>>>(
        ei, head, perm, dsts, h, WTe, WTv, be1, bv1, Qab, Pab, flags);

    fused_kernel<<<FWG, 256, 0, stream>>>(e, ei, perm, dsts,
                                          WT1c, WT2, be2, Qab,
                                          neg, neb, WvcT, Pab,
                                          S, d_out, flags);
    hn_gemm_kernel<<<(NNODE + 63) / 64, 256, 0, stream>>>(S, WTv2, bv2, cnt, h,
                                                          nvg, nvb, d_out, flags);
}

// Round 19
// 326.559 us; speedup vs baseline: 1.0404x; 1.0404x over previous
//
#include <hip/hip_runtime.h>
#include <hip/hip_bf16.h>

#define NNODE 10000
#define NEDGE 160000
#define HIDD  256
#define ED    128
#define CAT   640

typedef short bf8 __attribute__((ext_vector_type(8)));
typedef short bf4 __attribute__((ext_vector_type(4)));
typedef float f4  __attribute__((ext_vector_type(4)));
typedef unsigned int u32;

__device__ __forceinline__ float bf2f(ushort u) {
    return __uint_as_float(((unsigned)u) << 16);
}
__device__ __forceinline__ ushort f2bf(float f) {
    unsigned u = __float_as_uint(f);
    return (ushort)((u + 0x7fffu + ((u >> 16) & 1u)) >> 16);
}
__device__ __forceinline__ float gelu_fast(float x) {
    float x2 = x * x;
    float u = 0.7978845608028654f * x * (1.0f + 0.044715f * x2);
    float au = fabsf(u);
    float ex = __expf(2.0f * au);
    float t = 1.0f - 2.0f / (1.0f + ex);
    t = copysignf(t, u);
    return 0.5f * x * (1.0f + t);
}
__device__ __forceinline__ int clampi(int v) {
    return ((unsigned)v >= (unsigned)NNODE) ? 0 : v;
}
__device__ __forceinline__ int getidx(const int* ei, bool i64, int pos) {
    int v = i64 ? ei[2 * pos] : ei[pos];
    return clampi(v);
}
__device__ __forceinline__ float loadf(const void* p, size_t idx, bool f32) {
    return f32 ? ((const float*)p)[idx] : bf2f(((const ushort*)p)[idx]);
}
__device__ __forceinline__ bf8 load8(const void* p, size_t idx, bool f32) {
    if (f32) {
        const float* fp = (const float*)p + idx;
        f4 lo = *(const f4*)fp, hi = *(const f4*)(fp + 4);
        bf8 r;
        r[0] = (short)f2bf(lo[0]); r[1] = (short)f2bf(lo[1]);
        r[2] = (short)f2bf(lo[2]); r[3] = (short)f2bf(lo[3]);
        r[4] = (short)f2bf(hi[0]); r[5] = (short)f2bf(hi[1]);
        r[6] = (short)f2bf(hi[2]); r[7] = (short)f2bf(hi[3]);
        return r;
    }
    return *(const bf8*)((const ushort*)p + idx);
}
__device__ __forceinline__ void storef(void* p, size_t idx, float v, bool f32) {
    if (f32) ((float*)p)[idx] = v;
    else     ((ushort*)p)[idx] = f2bf(v);
}
__device__ __forceinline__ void fadd_native(float* p, float v) {
    unsafeAtomicAdd(p, v);
}
// async global->LDS, 16B/lane; LDS dest = wave-uniform base + lane*16
__device__ __forceinline__ void gload16(const void* g, void* l) {
    __builtin_amdgcn_global_load_lds(
        (const __attribute__((address_space(1))) void*)g,
        (__attribute__((address_space(3))) void*)l, 16, 0, 0);
}
__device__ __forceinline__ void detect_local(const u32* h_u32, const u32* ei_u32,
                                             u32* sf) {
    if (threadIdx.x < 64) {
        int t = threadIdx.x;
        u32 e8 = (h_u32[t] >> 7) & 0xFFu;
        bool inw = (e8 >= 100u && e8 <= 150u);
        unsigned long long m = __ballot(inw);
        bool hi_nz = (t < 16) ? (ei_u32[2 * t + 1] != 0u) : false;
        unsigned long long m2 = __ballot(hi_nz);
        if (t == 0) {
            sf[0] = (__popcll(m) < 40) ? 1u : 0u;
            sf[1] = (m2 == 0ull) ? 1u : 0u;
        }
    }
    __syncthreads();
}

// ============ combo: prep (1280) + hconv (1250) + count (625) ============
// WT1c/WT2/WvcT stored PRE-SWIZZLED: elem k at position k ^ ((n&7)<<3)
#define PREP_B 1280
#define HCONV_B 1250
#define COUNT_B 625
__global__ __launch_bounds__(256) void combo_kernel(
    const void* __restrict__ h, const int* __restrict__ ei,
    const void* __restrict__ We1, const void* __restrict__ We2,
    const void* __restrict__ Wv1, const void* __restrict__ Wv2,
    ushort* __restrict__ WT, ushort* __restrict__ hb,
    u32* __restrict__ cnt, u32* __restrict__ flags)
{
    __shared__ u32 sf[2];
    detect_local((const u32*)h, (const u32*)ei, sf);
    const bool f32 = sf[0] != 0, i64 = sf[1] != 0;
    int b = blockIdx.x, tid = threadIdx.x;

    if (b == 0 && tid == 0) { flags[0] = sf[0]; flags[1] = sf[1]; }

    if (b < PREP_B) {
        int idx = b * 256 + tid;
        if (idx >= 327680) return;
        const void* W; int base, k0, K, Wld; bool swz = false;
        if      (idx <  32768) { W = We1; base = 0;      k0 = 0;   K = 256; Wld = 128; }
        else if (idx <  65536) { W = We1; base = 32768;  k0 = 256; K = 256; Wld = 128; }
        else if (idx <  81920) { W = We1; base = 65536;  k0 = 512; K = 128; Wld = 128; swz = true; }
        else if (idx <  98304) { W = We2; base = 81920;  k0 = 0;   K = 128; Wld = 128; swz = true; }
        else if (idx < 163840) { W = Wv1; base = 98304;  k0 = 0;   K = 256; Wld = 256; }
        else if (idx < 229376) { W = Wv1; base = 163840; k0 = 256; K = 256; Wld = 256; }
        else if (idx < 262144) { W = Wv1; base = 229376; k0 = 512; K = 128; Wld = 256; swz = true; }
        else                   { W = Wv2; base = 262144; k0 = 0;   K = 256; Wld = 256; }
        int local = idx - base;
        int k = local & (K - 1);
        int n = local / K;
        int kd = swz ? (k ^ ((n & 7) << 3)) : k;
        WT[base + n * K + kd] = f2bf(loadf(W, (size_t)(k0 + k) * Wld + n, f32));
    } else if (b < PREP_B + HCONV_B) {
        int i = (b - PREP_B) * 256 + tid;
        if (i < NNODE * HIDD / 8)
            *(bf8*)&hb[(size_t)i * 8] = load8(h, (size_t)i * 8, f32);
    } else {
        int i = (b - PREP_B - HCONV_B) * 256 + tid;
        if (i < NEDGE) atomicAdd(&cnt[getidx(ei, i64, NEDGE + i)], 1u);
    }
}

// ---- exclusive prefix scan over cnt -> head ----
__global__ void scan_kernel(const u32* __restrict__ cnt, int* __restrict__ head) {
    __shared__ u32 part[256];
    __shared__ u32 base[256];
    int t = threadIdx.x;
    u32 s = 0;
    for (int j = 0; j < 40; ++j) {
        int i = t * 40 + j;
        if (i < NNODE) s += cnt[i];
    }
    part[t] = s;
    __syncthreads();
    if (t == 0) {
        u32 run = 0;
        for (int i = 0; i < 256; ++i) { base[i] = run; run += part[i]; }
    }
    __syncthreads();
    u32 run = base[t];
    for (int j = 0; j < 40; ++j) {
        int i = t * 40 + j;
        if (i < NNODE) { head[i] = (int)run; run += cnt[i]; }
    }
}

// ---- node-level projections, permuted layout + bias folding ----
template<int NB>
__device__ __forceinline__ void qp_body(const ushort* __restrict__ hb,
                                        const ushort* __restrict__ WT,
                                        const void* __restrict__ bias,
                                        ushort* __restrict__ O, int bid, bool f32) {
    const int tid = threadIdx.x;
    const int wid = tid >> 6, lane = tid & 63;
    const int l16 = lane & 15, lg = lane >> 4;
    const int node0 = bid * 64;
    const int N = NB * 64;
    const int n0 = wid * (NB * 16);

    size_t ra[4];
    #pragma unroll
    for (int ai = 0; ai < 4; ++ai) {
        int row = node0 + ai * 16 + l16;
        ra[ai] = (size_t)(row < NNODE ? row : NNODE - 1) * HIDD;
    }
    int bb[NB];
    #pragma unroll
    for (int bi = 0; bi < NB; ++bi) bb[bi] = (n0 + bi * 16 + l16) * HIDD;

    f4 acc[4][NB] = {};
    for (int kc = 0; kc < 4; ++kc) {
        #pragma unroll
        for (int ks = 0; ks < 2; ++ks) {
            int kk = kc * 64 + ks * 32 + lg * 8;
            bf8 b[NB];
            #pragma unroll
            for (int bi = 0; bi < NB; ++bi) b[bi] = *(const bf8*)&WT[bb[bi] + kk];
            #pragma unroll
            for (int ai = 0; ai < 4; ++ai) {
                bf8 a = *(const bf8*)&hb[ra[ai] + kk];
                #pragma unroll
                for (int bi = 0; bi < NB; ++bi)
                    acc[ai][bi] = __builtin_amdgcn_mfma_f32_16x16x32_bf16(a, b[bi], acc[ai][bi], 0, 0, 0);
            }
        }
    }
    #pragma unroll
    for (int bi = 0; bi < NB; ++bi) {
        int col = n0 + bi * 16 + l16;
        int pcol; float badd;
        if constexpr (NB == 4) {
            int hh = col >> 7, c = col & 127;
            badd = (hh == 0) ? loadf(bias, c, f32) : 0.f;
            pcol = hh * 128 + (c & 15) * 8 + (c >> 4);
        } else {
            int hh = col >> 8, c = col & 255;
            badd = (hh == 0) ? loadf(bias, c, f32) : 0.f;
            int nh2 = c >> 7, rem = c & 127, w = rem >> 5, b2 = (rem >> 4) & 1, l = c & 15;
            pcol = hh * 256 + w * 64 + l * 4 + nh2 * 2 + b2;
        }
        #pragma unroll
        for (int ai = 0; ai < 4; ++ai)
            #pragma unroll
            for (int r = 0; r < 4; ++r) {
                int gr = node0 + ai * 16 + lg * 4 + r;
                if (gr < NNODE) O[(size_t)gr * N + pcol] = f2bf(acc[ai][bi][r] + badd);
            }
    }
}

// ============ fill (625) + qp2 merged ============
#define QPB ((NNODE + 63) / 64)
#define FILL_B 625
__global__ __launch_bounds__(256) void fillqp_kernel(
    const int* __restrict__ ei, int* __restrict__ head,
    int* __restrict__ perm, int* __restrict__ dsts,
    const ushort* __restrict__ hb, const ushort* __restrict__ WTe,
    const ushort* __restrict__ WTv, const void* __restrict__ be1,
    const void* __restrict__ bv1, ushort* __restrict__ Qab,
    ushort* __restrict__ Pab, const u32* __restrict__ flags)
{
    const bool f32 = flags[0] != 0, i64 = flags[1] != 0;
    int b = blockIdx.x;
    if (b < FILL_B) {
        int i = b * 256 + threadIdx.x;
        if (i < NEDGE) {
            int d = getidx(ei, i64, NEDGE + i);
            int pos = atomicAdd(&head[d], 1);
            perm[pos] = i;
            dsts[pos] = d;
        }
    } else if (b < FILL_B + QPB) {
        qp_body<4>(hb, WTe, be1, Qab, b - FILL_B, f32);
    } else {
        qp_body<8>(hb, WTv, bv1, Pab, b - FILL_B - QPB, f32);
    }
}

// ============ FUSED edge+node1 (dst-sorted), 64 edges/block, 256 thr ============
// Weights staged via global_load_lds into linear Bsm (pre-swizzled source, XOR read)
#define FWG (NEDGE / 64)   // 2500 blocks
__global__ __launch_bounds__(256) void fused_kernel(
    const void* __restrict__ e, const int* __restrict__ ei,
    const int* __restrict__ perm, const int* __restrict__ dsts,
    const ushort* __restrict__ WT1c,
    const ushort* __restrict__ WT2, const void* __restrict__ be2,
    const ushort* __restrict__ Qab,
    const void* __restrict__ neg, const void* __restrict__ neb,
    const ushort* __restrict__ WvcT,
    const ushort* __restrict__ Pab,
    float* __restrict__ S, void* __restrict__ out,
    const u32* __restrict__ flags)
{
    const bool f32 = flags[0] != 0, i64 = flags[1] != 0;
    __shared__ ushort Asm[64 * 136];    // 17408 B (padded, vector-staged)
    __shared__ ushort Bsm[128 * 128];   // 32768 B (LINEAR, gload_lds, swizzled data)
    __shared__ ushort Tsm[64 * 136];    // 17408 B
    __shared__ int PermS[64], SrcS[64], DstS[64];   // 768 B -> 68352 B total

    int orig = blockIdx.x;
    int xcd = orig & 7, slot = orig >> 3;
    int bid = (xcd < 4 ? xcd * 313 : 4 * 313 + (xcd - 4) * 312) + slot;

    const int tid = threadIdx.x;
    const int wid = tid >> 6, lane = tid & 63;
    const int l16 = lane & 15, lg = lane >> 4;
    const int edge0 = bid * 64;
    const int rm = wid * 16;
    const int sx = (l16 & 7) << 3;     // XOR for swizzled B reads

    if (tid < 64) {
        int eid = perm[edge0 + tid];
        PermS[tid] = eid;
        SrcS[tid] = getidx(ei, i64, eid);
        DstS[tid] = dsts[edge0 + tid];
    }
    __syncthreads();

    // ---- stage B phase-1 (gload, linear) + A (e rows, vector) ----
    #pragma unroll
    for (int it = 0; it < 8; ++it) {
        int r0 = it * 16 + wid * 4;
        gload16(WT1c + (size_t)(r0 + (lane >> 4)) * 128 + (lane & 15) * 8,
                &Bsm[r0 * 128]);
    }
    #pragma unroll
    for (int j = 0; j < 4; ++j) {
        int s2 = tid + j * 256;
        int r = s2 >> 4, c8 = (s2 & 15) * 8;
        *(bf8*)&Asm[r * 136 + c8] = load8(e, (size_t)PermS[r] * ED + c8, f32);
    }
    __syncthreads();

    // ---------- phase 1: T1 = e @ WT1c^T (K=128) ----------
    f4 acc[8] = {};
    #pragma unroll
    for (int kc = 0; kc < 2; ++kc)
        #pragma unroll
        for (int ks = 0; ks < 2; ++ks) {
            int ko = kc * 64 + ks * 32 + lg * 8;
            int kos = ko ^ sx;
            bf8 a = *(const bf8*)&Asm[(rm + l16) * 136 + ko];
            #pragma unroll
            for (int f = 0; f < 8; ++f) {
                bf8 b = *(const bf8*)&Bsm[(f * 16 + l16) * 128 + kos];
                acc[f] = __builtin_amdgcn_mfma_f32_16x16x32_bf16(a, b, acc[f], 0, 0, 0);
            }
        }

    // epilogue 1: + (be1 in Qab) + Qa[src] + Qb[dst], gelu -> Tsm
    {
        bf8 qs[4], qd[4];
        #pragma unroll
        for (int r = 0; r < 4; ++r) {
            int row = rm + lg * 4 + r;
            qs[r] = *(const bf8*)&Qab[(size_t)SrcS[row] * 256 + l16 * 8];
            qd[r] = *(const bf8*)&Qab[(size_t)DstS[row] * 256 + 128 + l16 * 8];
        }
        #pragma unroll
        for (int f = 0; f < 8; ++f)
            #pragma unroll
            for (int r = 0; r < 4; ++r) {
                float val = acc[f][r] + bf2f((ushort)qs[r][f]) + bf2f((ushort)qd[r][f]);
                Tsm[(rm + lg * 4 + r) * 136 + f * 16 + l16] = f2bf(gelu_fast(val));
            }
    }
    __syncthreads();   // protect Bsm overwrite

    // ---- stage B phase-2 ----
    #pragma unroll
    for (int it = 0; it < 8; ++it) {
        int r0 = it * 16 + wid * 4;
        gload16(WT2 + (size_t)(r0 + (lane >> 4)) * 128 + (lane & 15) * 8,
                &Bsm[r0 * 128]);
    }
    __syncthreads();

    // ---------- phase 2: T2 = T1 @ WT2^T (K=128) ----------
    f4 acc2[8] = {};
    #pragma unroll
    for (int kc = 0; kc < 2; ++kc)
        #pragma unroll
        for (int ks = 0; ks < 2; ++ks) {
            int ko = kc * 64 + ks * 32 + lg * 8;
            int kos = ko ^ sx;
            bf8 a = *(const bf8*)&Tsm[(rm + l16) * 136 + ko];
            #pragma unroll
            for (int f = 0; f < 8; ++f) {
                bf8 b = *(const bf8*)&Bsm[(f * 16 + l16) * 128 + kos];
                acc2[f] = __builtin_amdgcn_mfma_f32_16x16x32_bf16(a, b, acc2[f], 0, 0, 0);
            }
        }

    // epilogue 2: + be2 + e residual (from Asm), LN -> Tsm (bf16 e_new)
    {
        float v[8][4];
        #pragma unroll
        for (int f = 0; f < 8; ++f) {
            int col = f * 16 + l16;
            float bias = loadf(be2, col, f32);
            #pragma unroll
            for (int r = 0; r < 4; ++r) {
                int row = rm + lg * 4 + r;
                v[f][r] = acc2[f][r] + bias + bf2f(Asm[row * 136 + col]);
            }
        }
        #pragma unroll
        for (int r = 0; r < 4; ++r) {
            float s = 0.f;
            #pragma unroll
            for (int f = 0; f < 8; ++f) s += v[f][r];
            s += __shfl_xor(s, 1); s += __shfl_xor(s, 2);
            s += __shfl_xor(s, 4); s += __shfl_xor(s, 8);
            float mu = s * (1.0f / 128.0f);
            float q = 0.f;
            #pragma unroll
            for (int f = 0; f < 8; ++f) { float d = v[f][r] - mu; q += d * d; }
            q += __shfl_xor(q, 1); q += __shfl_xor(q, 2);
            q += __shfl_xor(q, 4); q += __shfl_xor(q, 8);
            float rstd = rsqrtf(q * (1.0f / 128.0f) + 1e-5f);
            int row = rm + lg * 4 + r;
            #pragma unroll
            for (int f = 0; f < 8; ++f) {
                int col = f * 16 + l16;
                float y = (v[f][r] - mu) * rstd * loadf(neg, col, f32) + loadf(neb, col, f32);
                Tsm[row * 136 + col] = f2bf(y);
            }
        }
    }
    __syncthreads();   // publish e_new cross-wave

    // ---- hoisted Pab gathers (hidden under e_new write + phase-3) ----
    bf4 ps[4][4], pd[4][4];
    #pragma unroll
    for (int ai = 0; ai < 4; ++ai) {
        int p0 = ai * 16 + lg * 4;
        #pragma unroll
        for (int r = 0; r < 4; ++r) {
            ps[ai][r] = *(const bf4*)&Pab[(size_t)SrcS[p0 + r] * 512 + wid * 64 + l16 * 4];
            pd[ai][r] = *(const bf4*)&Pab[(size_t)DstS[p0 + r] * 512 + 256 + wid * 64 + l16 * 4];
        }
    }

    // ---- bulk e_new global write from Tsm ----
    {
        int row = tid >> 2, pc = (tid & 3) * 32;
        size_t obase = (size_t)NNODE * HIDD + (size_t)PermS[row] * ED + pc;
        #pragma unroll
        for (int q2 = 0; q2 < 4; ++q2) {
            bf8 w = *(const bf8*)&Tsm[row * 136 + pc + q2 * 8];
            if (f32) {
                f4 lo, hi;
                lo[0] = bf2f((ushort)w[0]); lo[1] = bf2f((ushort)w[1]);
                lo[2] = bf2f((ushort)w[2]); lo[3] = bf2f((ushort)w[3]);
                hi[0] = bf2f((ushort)w[4]); hi[1] = bf2f((ushort)w[5]);
                hi[2] = bf2f((ushort)w[6]); hi[3] = bf2f((ushort)w[7]);
                *(f4*)((float*)out + obase + q2 * 8) = lo;
                *(f4*)((float*)out + obase + q2 * 8 + 4) = hi;
            } else {
                *(bf8*)((ushort*)out + obase + q2 * 8) = w;
            }
        }
    }

    // ---------- phase 3: U = e_new @ WvcT^T (K=128, N=256 in 2 halves) ----------
    f4 accN[4][2][2] = {};
    #pragma unroll
    for (int nh = 0; nh < 2; ++nh) {
        #pragma unroll
        for (int it = 0; it < 8; ++it) {
            int r0 = it * 16 + wid * 4;
            gload16(WvcT + (size_t)(nh * 128 + r0 + (lane >> 4)) * 128 + (lane & 15) * 8,
                    &Bsm[r0 * 128]);
        }
        __syncthreads();
        #pragma unroll
        for (int kc = 0; kc < 2; ++kc)
            #pragma unroll
            for (int ks = 0; ks < 2; ++ks) {
                int ko = kc * 64 + ks * 32 + lg * 8;
                int kos = ko ^ sx;
                bf8 a[4], b[2];
                #pragma unroll
                for (int ai = 0; ai < 4; ++ai)
                    a[ai] = *(const bf8*)&Tsm[(ai * 16 + l16) * 136 + ko];
                #pragma unroll
                for (int bi = 0; bi < 2; ++bi)
                    b[bi] = *(const bf8*)&Bsm[(wid * 32 + bi * 16 + l16) * 128 + kos];
                #pragma unroll
                for (int ai = 0; ai < 4; ++ai)
                    #pragma unroll
                    for (int bi = 0; bi < 2; ++bi)
                        accN[ai][nh][bi] = __builtin_amdgcn_mfma_f32_16x16x32_bf16(a[ai], b[bi], accN[ai][nh][bi], 0, 0, 0);
            }
        __syncthreads();
    }

    // epilogue 3: + (bv1 in Pab) + Pa[src] + Pb[dst] (pre-gathered), merged scatter
    #pragma unroll
    for (int ai = 0; ai < 4; ++ai) {
        int p0 = ai * 16 + lg * 4;
        int dd[4];
        #pragma unroll
        for (int r = 0; r < 4; ++r) dd[r] = DstS[p0 + r];
        #pragma unroll
        for (int nh = 0; nh < 2; ++nh)
            #pragma unroll
            for (int bi = 0; bi < 2; ++bi) {
                int col = nh * 128 + wid * 32 + bi * 16 + l16;
                const int j = nh * 2 + bi;
                float v0 = gelu_fast(accN[ai][nh][bi][0] + bf2f((ushort)ps[ai][0][j]) + bf2f((ushort)pd[ai][0][j]));
                float v1 = gelu_fast(accN[ai][nh][bi][1] + bf2f((ushort)ps[ai][1][j]) + bf2f((ushort)pd[ai][1][j]));
                float v2 = gelu_fast(accN[ai][nh][bi][2] + bf2f((ushort)ps[ai][2][j]) + bf2f((ushort)pd[ai][2][j]));
                float v3 = gelu_fast(accN[ai][nh][bi][3] + bf2f((ushort)ps[ai][3][j]) + bf2f((ushort)pd[ai][3][j]));
                float s = v0; int d = dd[0];
                if (dd[1] == d) s += v1; else { fadd_native(&S[(size_t)d * HIDD + col], s); d = dd[1]; s = v1; }
                if (dd[2] == d) s += v2; else { fadd_native(&S[(size_t)d * HIDD + col], s); d = dd[2]; s = v2; }
                if (dd[3] == d) s += v3; else { fadd_native(&S[(size_t)d * HIDD + col], s); d = dd[3]; s = v3; }
                fadd_native(&S[(size_t)d * HIDD + col], s);
            }
    }
}

// ---- node phase 2 + LN ----
__global__ __launch_bounds__(256) void hn_gemm_kernel(
    const float* __restrict__ S, const ushort* __restrict__ WTv2,
    const void* __restrict__ bv2, const u32* __restrict__ cnt,
    const void* __restrict__ h,
    const void* __restrict__ nvg, const void* __restrict__ nvb,
    void* __restrict__ out, const u32* __restrict__ flags)
{
    const bool f32 = flags[0] != 0;
    constexpr int LDV = 260;
    __shared__ float Vsm[64 * LDV];

    const int tid = threadIdx.x;
    const int wid = tid >> 6, lane = tid & 63;
    const int l16 = lane & 15, lg = lane >> 4;
    const int node0 = blockIdx.x * 64;
    const int n0 = wid * 64;

    size_t ra[4];
    #pragma unroll
    for (int ai = 0; ai < 4; ++ai) {
        int row = node0 + ai * 16 + l16;
        ra[ai] = (size_t)(row < NNODE ? row : NNODE - 1) * HIDD;
    }
    int bb[4];
    #pragma unroll
    for (int bi = 0; bi < 4; ++bi) bb[bi] = (n0 + bi * 16 + l16) * HIDD;

    f4 acc[4][4] = {};
    for (int kc = 0; kc < 4; ++kc) {
        #pragma unroll
        for (int ks = 0; ks < 2; ++ks) {
            int kk = kc * 64 + ks * 32 + lg * 8;
            bf8 b[4];
            #pragma unroll
            for (int bi = 0; bi < 4; ++bi) b[bi] = *(const bf8*)&WTv2[bb[bi] + kk];
            #pragma unroll
            for (int ai = 0; ai < 4; ++ai) {
                bf8 a = load8(S, ra[ai] + kk, true);
                #pragma unroll
                for (int bi = 0; bi < 4; ++bi)
                    acc[ai][bi] = __builtin_amdgcn_mfma_f32_16x16x32_bf16(a, b[bi], acc[ai][bi], 0, 0, 0);
            }
        }
    }

    #pragma unroll
    for (int bi = 0; bi < 4; ++bi) {
        int col = n0 + bi * 16 + l16;
        float b2 = loadf(bv2, col, f32);
        #pragma unroll
        for (int ai = 0; ai < 4; ++ai)
            #pragma unroll
            for (int r = 0; r < 4; ++r) {
                int rowl = ai * 16 + lg * 4 + r;
                int gr = node0 + rowl;
                int grc = gr < NNODE ? gr : NNODE - 1;
                float c = (float)cnt[grc];
                float inv = 1.0f / fmaxf(c, 1.0f);
                float val = (acc[ai][bi][r] + c * b2) * inv
                          + loadf(h, (size_t)grc * HIDD + col, f32);
                Vsm[rowl * LDV + col] = val;
            }
    }
    __syncthreads();

    #pragma unroll
    for (int rr = 0; rr < 4; ++rr) {
        int rowl = wid * 16 + lg * 4 + rr;
        int gr = node0 + rowl;
        float x[16];
        #pragma unroll
        for (int f = 0; f < 16; ++f) x[f] = Vsm[rowl * LDV + f * 16 + l16];
        float s = 0.f;
        #pragma unroll
        for (int f = 0; f < 16; ++f) s += x[f];
        s += __shfl_xor(s, 1); s += __shfl_xor(s, 2);
        s += __shfl_xor(s, 4); s += __shfl_xor(s, 8);
        float mu = s * (1.0f / 256.0f);
        float q = 0.f;
        #pragma unroll
        for (int f = 0; f < 16; ++f) { float d = x[f] - mu; q += d * d; }
        q += __shfl_xor(q, 1); q += __shfl_xor(q, 2);
        q += __shfl_xor(q, 4); q += __shfl_xor(q, 8);
        float rstd = rsqrtf(q * (1.0f / 256.0f) + 1e-5f);
        if (gr < NNODE) {
            #pragma unroll
            for (int f = 0; f < 16; ++f) {
                int col = f * 16 + l16;
                float y = (x[f] - mu) * rstd * loadf(nvg, col, f32) + loadf(nvb, col, f32);
                storef(out, (size_t)gr * HIDD + col, y, f32);
            }
        }
    }
}

extern "C" void kernel_launch(void* const* d_in, const int* in_sizes, int n_in,
                              void* d_out, int out_size, void* d_ws, size_t ws_size,
                              hipStream_t stream)
{
    (void)in_sizes; (void)n_in; (void)out_size; (void)ws_size;
    const void* h   = d_in[0];
    const void* e   = d_in[1];
    const int*  ei  = (const int*)d_in[2];
    const void* We1 = d_in[3];
    const void* be1 = d_in[4];
    const void* We2 = d_in[5];
    const void* be2 = d_in[6];
    const void* Wv1 = d_in[7];
    const void* bv1 = d_in[8];
    const void* Wv2 = d_in[9];
    const void* bv2 = d_in[10];
    const void* neg = d_in[11];
    const void* neb = d_in[12];
    const void* nvg = d_in[13];
    const void* nvb = d_in[14];

    char* ws = (char*)d_ws;
    u32*   flags = (u32*)ws;
    float* S     = (float*)(ws + 256);
    u32*   cnt   = (u32*)(ws + 256 + (size_t)NNODE * HIDD * 4);
    size_t off = 256 + (size_t)NNODE * HIDD * 4 + ((size_t)NNODE * 4 + 255) / 256 * 256;
    int*   head = (int*)(ws + off);            off += ((size_t)NNODE * 4 + 255) / 256 * 256;
    int*   perm = (int*)(ws + off);            off += (size_t)NEDGE * 4;
    int*   dsts = (int*)(ws + off);            off += (size_t)NEDGE * 4;
    ushort* WTb  = (ushort*)(ws + off);
    ushort* WTe  = WTb;                        // [256][256]
    ushort* WT1c = WTb + 65536;                // [128][128] swizzled
    ushort* WT2  = WTb + 81920;                // [128][128] swizzled
    ushort* WTv  = WTb + 98304;                // [512][256]
    ushort* WvcT = WTb + 229376;               // [256][128] swizzled
    ushort* WTv2 = WTb + 262144;               // [256][256]
    ushort* hb   = WTb + 327680;                       // [10000][256] bf16
    ushort* Qab  = hb + (size_t)NNODE * HIDD;          // [10000][256] bf16 (permuted)
    ushort* Pab  = Qab + (size_t)NNODE * 256;          // [10000][512] bf16 (permuted)

    hipMemsetAsync(S, 0, (size_t)NNODE * HIDD * 4 + (size_t)NNODE * 4, stream);

    combo_kernel<<<PREP_B + HCONV_B + COUNT_B, 256, 0, stream>>>(
        h, ei, We1, We2, Wv1, Wv2, WTb, hb, cnt, flags);
    scan_kernel<<<1, 256, 0, stream>>>(cnt, head);
    fillqp_kernel<<<FILL_B + 2 * QPB, 256, 0, stream>>>(
        ei, head, perm, dsts, hb, WTe, WTv, be1, bv1, Qab, Pab, flags);

    fused_kernel<<<FWG, 256, 0, stream>>>(e, ei, perm, dsts,
                                          WT1c, WT2, be2, Qab,
                                          neg, neb, WvcT, Pab,
                                          S, d_out, flags);
    hn_gemm_kernel<<<(NNODE + 63) / 64, 256, 0, stream>>>(S, WTv2, bv2, cnt, h,
                                                          nvg, nvb, d_out, flags);
}

// Round 20
// 315.085 us; speedup vs baseline: 1.0782x; 1.0364x over previous
//
#include <hip/hip_runtime.h>
#include <hip/hip_bf16.h>

#define NNODE 10000
#define NEDGE 160000
#define HIDD  256
#define ED    128
#define CAT   640

typedef short bf8 __attribute__((ext_vector_type(8)));
typedef short bf4 __attribute__((ext_vector_type(4)));
typedef float f4  __attribute__((ext_vector_type(4)));
typedef unsigned int u32;

__device__ __forceinline__ float bf2f(ushort u) {
    return __uint_as_float(((unsigned)u) << 16);
}
__device__ __forceinline__ ushort f2bf(float f) {
    unsigned u = __float_as_uint(f);
    return (ushort)((u + 0x7fffu + ((u >> 16) & 1u)) >> 16);
}
__device__ __forceinline__ float gelu_fast(float x) {
    float x2 = x * x;
    float u = 0.7978845608028654f * x * (1.0f + 0.044715f * x2);
    float au = fabsf(u);
    float ex = __expf(2.0f * au);
    float t = 1.0f - 2.0f / (1.0f + ex);
    t = copysignf(t, u);
    return 0.5f * x * (1.0f + t);
}
__device__ __forceinline__ int clampi(int v) {
    return ((unsigned)v >= (unsigned)NNODE) ? 0 : v;
}
__device__ __forceinline__ int getidx(const int* ei, bool i64, int pos) {
    int v = i64 ? ei[2 * pos] : ei[pos];
    return clampi(v);
}
__device__ __forceinline__ float loadf(const void* p, size_t idx, bool f32) {
    return f32 ? ((const float*)p)[idx] : bf2f(((const ushort*)p)[idx]);
}
__device__ __forceinline__ bf8 load8(const void* p, size_t idx, bool f32) {
    if (f32) {
        const float* fp = (const float*)p + idx;
        f4 lo = *(const f4*)fp, hi = *(const f4*)(fp + 4);
        bf8 r;
        r[0] = (short)f2bf(lo[0]); r[1] = (short)f2bf(lo[1]);
        r[2] = (short)f2bf(lo[2]); r[3] = (short)f2bf(lo[3]);
        r[4] = (short)f2bf(hi[0]); r[5] = (short)f2bf(hi[1]);
        r[6] = (short)f2bf(hi[2]); r[7] = (short)f2bf(hi[3]);
        return r;
    }
    return *(const bf8*)((const ushort*)p + idx);
}
__device__ __forceinline__ void storef(void* p, size_t idx, float v, bool f32) {
    if (f32) ((float*)p)[idx] = v;
    else     ((ushort*)p)[idx] = f2bf(v);
}
__device__ __forceinline__ void fadd_native(float* p, float v) {
    unsafeAtomicAdd(p, v);
}
// async global->LDS, 16B/lane
__device__ __forceinline__ void gload16(const void* g, void* l) {
    __builtin_amdgcn_global_load_lds(
        (const __attribute__((address_space(1))) void*)g,
        (__attribute__((address_space(3))) void*)l, 16, 0, 0);
}
__device__ __forceinline__ void detect_local(const u32* h_u32, const u32* ei_u32,
                                             u32* sf) {
    if (threadIdx.x < 64) {
        int t = threadIdx.x;
        u32 e8 = (h_u32[t] >> 7) & 0xFFu;
        bool inw = (e8 >= 100u && e8 <= 150u);
        unsigned long long m = __ballot(inw);
        bool hi_nz = (t < 16) ? (ei_u32[2 * t + 1] != 0u) : false;
        unsigned long long m2 = __ballot(hi_nz);
        if (t == 0) {
            sf[0] = (__popcll(m) < 40) ? 1u : 0u;
            sf[1] = (m2 == 0ull) ? 1u : 0u;
        }
    }
    __syncthreads();
}

// ============ combo: prep (1280) + hconv (1250) + count (625) ============
// PREP reads coalesced (consecutive lanes -> consecutive n).
// WT1c/WT2/WvcT stored PRE-SWIZZLED: elem k at position k ^ ((n&7)<<3)
#define PREP_B 1280
#define HCONV_B 1250
#define COUNT_B 625
__global__ __launch_bounds__(256) void combo_kernel(
    const void* __restrict__ h, const int* __restrict__ ei,
    const void* __restrict__ We1, const void* __restrict__ We2,
    const void* __restrict__ Wv1, const void* __restrict__ Wv2,
    ushort* __restrict__ WT, ushort* __restrict__ hb,
    u32* __restrict__ cnt, u32* __restrict__ flags)
{
    __shared__ u32 sf[2];
    detect_local((const u32*)h, (const u32*)ei, sf);
    const bool f32 = sf[0] != 0, i64 = sf[1] != 0;
    int b = blockIdx.x, tid = threadIdx.x;

    if (b == 0 && tid == 0) { flags[0] = sf[0]; flags[1] = sf[1]; }

    if (b < PREP_B) {
        int idx = b * 256 + tid;
        if (idx >= 327680) return;
        const void* W; int base, k0, K, N, Wld; bool swz = false;
        if      (idx <  32768) { W = We1; base = 0;      k0 = 0;   K = 256; N = 128; Wld = 128; }
        else if (idx <  65536) { W = We1; base = 32768;  k0 = 256; K = 256; N = 128; Wld = 128; }
        else if (idx <  81920) { W = We1; base = 65536;  k0 = 512; K = 128; N = 128; Wld = 128; swz = true; }
        else if (idx <  98304) { W = We2; base = 81920;  k0 = 0;   K = 128; N = 128; Wld = 128; swz = true; }
        else if (idx < 163840) { W = Wv1; base = 98304;  k0 = 0;   K = 256; N = 256; Wld = 256; }
        else if (idx < 229376) { W = Wv1; base = 163840; k0 = 256; K = 256; N = 256; Wld = 256; }
        else if (idx < 262144) { W = Wv1; base = 229376; k0 = 512; K = 128; N = 256; Wld = 256; swz = true; }
        else                   { W = Wv2; base = 262144; k0 = 0;   K = 256; N = 256; Wld = 256; }
        int local = idx - base;
        int n = local & (N - 1);
        int k = local / N;
        int kd = swz ? (k ^ ((n & 7) << 3)) : k;
        WT[base + n * K + kd] = f2bf(loadf(W, (size_t)(k0 + k) * Wld + n, f32));
    } else if (b < PREP_B + HCONV_B) {
        int i = (b - PREP_B) * 256 + tid;
        if (i < NNODE * HIDD / 8)
            *(bf8*)&hb[(size_t)i * 8] = load8(h, (size_t)i * 8, f32);
    } else {
        int i = (b - PREP_B - HCONV_B) * 256 + tid;
        if (i < NEDGE) atomicAdd(&cnt[getidx(ei, i64, NEDGE + i)], 1u);
    }
}

// ---- exclusive prefix scan over cnt -> head ----
__global__ void scan_kernel(const u32* __restrict__ cnt, int* __restrict__ head) {
    __shared__ u32 part[256];
    __shared__ u32 base[256];
    int t = threadIdx.x;
    u32 s = 0;
    for (int j = 0; j < 40; ++j) {
        int i = t * 40 + j;
        if (i < NNODE) s += cnt[i];
    }
    part[t] = s;
    __syncthreads();
    if (t == 0) {
        u32 run = 0;
        for (int i = 0; i < 256; ++i) { base[i] = run; run += part[i]; }
    }
    __syncthreads();
    u32 run = base[t];
    for (int j = 0; j < 40; ++j) {
        int i = t * 40 + j;
        if (i < NNODE) { head[i] = (int)run; run += cnt[i]; }
    }
}

// ---- node-level projections, 32 nodes/block, permuted store + bias folding ----
template<int NB>
__device__ __forceinline__ void qp_body(const ushort* __restrict__ hb,
                                        const ushort* __restrict__ WT,
                                        const void* __restrict__ bias,
                                        ushort* __restrict__ O, int bid, bool f32) {
    const int tid = threadIdx.x;
    const int wid = tid >> 6, lane = tid & 63;
    const int l16 = lane & 15, lg = lane >> 4;
    const int node0 = bid * 32;
    const int N = NB * 64;
    const int n0 = wid * (NB * 16);

    size_t ra[2];
    #pragma unroll
    for (int ai = 0; ai < 2; ++ai) {
        int row = node0 + ai * 16 + l16;
        ra[ai] = (size_t)(row < NNODE ? row : NNODE - 1) * HIDD;
    }
    int bb[NB];
    #pragma unroll
    for (int bi = 0; bi < NB; ++bi) bb[bi] = (n0 + bi * 16 + l16) * HIDD;

    f4 acc[2][NB] = {};
    for (int kc = 0; kc < 4; ++kc) {
        #pragma unroll
        for (int ks = 0; ks < 2; ++ks) {
            int kk = kc * 64 + ks * 32 + lg * 8;
            bf8 b[NB];
            #pragma unroll
            for (int bi = 0; bi < NB; ++bi) b[bi] = *(const bf8*)&WT[bb[bi] + kk];
            #pragma unroll
            for (int ai = 0; ai < 2; ++ai) {
                bf8 a = *(const bf8*)&hb[ra[ai] + kk];
                #pragma unroll
                for (int bi = 0; bi < NB; ++bi)
                    acc[ai][bi] = __builtin_amdgcn_mfma_f32_16x16x32_bf16(a, b[bi], acc[ai][bi], 0, 0, 0);
            }
        }
    }
    #pragma unroll
    for (int bi = 0; bi < NB; ++bi) {
        int col = n0 + bi * 16 + l16;
        int pcol; float badd;
        if constexpr (NB == 4) {
            int hh = col >> 7, c = col & 127;
            badd = (hh == 0) ? loadf(bias, c, f32) : 0.f;
            pcol = hh * 128 + (c & 15) * 8 + (c >> 4);
        } else {
            int hh = col >> 8, c = col & 255;
            badd = (hh == 0) ? loadf(bias, c, f32) : 0.f;
            int nh2 = c >> 7, rem = c & 127, w = rem >> 5, b2 = (rem >> 4) & 1, l = c & 15;
            pcol = hh * 256 + w * 64 + l * 4 + nh2 * 2 + b2;
        }
        #pragma unroll
        for (int ai = 0; ai < 2; ++ai)
            #pragma unroll
            for (int r = 0; r < 4; ++r) {
                int gr = node0 + ai * 16 + lg * 4 + r;
                if (gr < NNODE) O[(size_t)gr * N + pcol] = f2bf(acc[ai][bi][r] + badd);
            }
    }
}

// ============ fill (625) + qp2 merged ============
#define QPB32 ((NNODE + 31) / 32)
#define FILL_B 625
__global__ __launch_bounds__(256) void fillqp_kernel(
    const int* __restrict__ ei, int* __restrict__ head,
    int* __restrict__ perm, int* __restrict__ dsts,
    const ushort* __restrict__ hb, const ushort* __restrict__ WTe,
    const ushort* __restrict__ WTv, const void* __restrict__ be1,
    const void* __restrict__ bv1, ushort* __restrict__ Qab,
    ushort* __restrict__ Pab, const u32* __restrict__ flags)
{
    const bool f32 = flags[0] != 0, i64 = flags[1] != 0;
    int b = blockIdx.x;
    if (b < FILL_B) {
        int i = b * 256 + threadIdx.x;
        if (i < NEDGE) {
            int d = getidx(ei, i64, NEDGE + i);
            int pos = atomicAdd(&head[d], 1);
            perm[pos] = i;
            dsts[pos] = d;
        }
    } else if (b < FILL_B + QPB32) {
        qp_body<4>(hb, WTe, be1, Qab, b - FILL_B, f32);
    } else {
        qp_body<8>(hb, WTv, bv1, Pab, b - FILL_B - QPB32, f32);
    }
}

// ============ FUSED edge+node1 (unchanged from round 19) ============
#define FWG (NEDGE / 64)   // 2500 blocks
__global__ __launch_bounds__(256) void fused_kernel(
    const void* __restrict__ e, const int* __restrict__ ei,
    const int* __restrict__ perm, const int* __restrict__ dsts,
    const ushort* __restrict__ WT1c,
    const ushort* __restrict__ WT2, const void* __restrict__ be2,
    const ushort* __restrict__ Qab,
    const void* __restrict__ neg, const void* __restrict__ neb,
    const ushort* __restrict__ WvcT,
    const ushort* __restrict__ Pab,
    float* __restrict__ S, void* __restrict__ out,
    const u32* __restrict__ flags)
{
    const bool f32 = flags[0] != 0, i64 = flags[1] != 0;
    __shared__ ushort Asm[64 * 136];
    __shared__ ushort Bsm[128 * 128];
    __shared__ ushort Tsm[64 * 136];
    __shared__ int PermS[64], SrcS[64], DstS[64];

    int orig = blockIdx.x;
    int xcd = orig & 7, slot = orig >> 3;
    int bid = (xcd < 4 ? xcd * 313 : 4 * 313 + (xcd - 4) * 312) + slot;

    const int tid = threadIdx.x;
    const int wid = tid >> 6, lane = tid & 63;
    const int l16 = lane & 15, lg = lane >> 4;
    const int edge0 = bid * 64;
    const int rm = wid * 16;
    const int sx = (l16 & 7) << 3;

    if (tid < 64) {
        int eid = perm[edge0 + tid];
        PermS[tid] = eid;
        SrcS[tid] = getidx(ei, i64, eid);
        DstS[tid] = dsts[edge0 + tid];
    }
    __syncthreads();

    #pragma unroll
    for (int it = 0; it < 8; ++it) {
        int r0 = it * 16 + wid * 4;
        gload16(WT1c + (size_t)(r0 + (lane >> 4)) * 128 + (lane & 15) * 8,
                &Bsm[r0 * 128]);
    }
    #pragma unroll
    for (int j = 0; j < 4; ++j) {
        int s2 = tid + j * 256;
        int r = s2 >> 4, c8 = (s2 & 15) * 8;
        *(bf8*)&Asm[r * 136 + c8] = load8(e, (size_t)PermS[r] * ED + c8, f32);
    }
    __syncthreads();

    // phase 1
    f4 acc[8] = {};
    #pragma unroll
    for (int kc = 0; kc < 2; ++kc)
        #pragma unroll
        for (int ks = 0; ks < 2; ++ks) {
            int ko = kc * 64 + ks * 32 + lg * 8;
            int kos = ko ^ sx;
            bf8 a = *(const bf8*)&Asm[(rm + l16) * 136 + ko];
            #pragma unroll
            for (int f = 0; f < 8; ++f) {
                bf8 b = *(const bf8*)&Bsm[(f * 16 + l16) * 128 + kos];
                acc[f] = __builtin_amdgcn_mfma_f32_16x16x32_bf16(a, b, acc[f], 0, 0, 0);
            }
        }

    {
        bf8 qs[4], qd[4];
        #pragma unroll
        for (int r = 0; r < 4; ++r) {
            int row = rm + lg * 4 + r;
            qs[r] = *(const bf8*)&Qab[(size_t)SrcS[row] * 256 + l16 * 8];
            qd[r] = *(const bf8*)&Qab[(size_t)DstS[row] * 256 + 128 + l16 * 8];
        }
        #pragma unroll
        for (int f = 0; f < 8; ++f)
            #pragma unroll
            for (int r = 0; r < 4; ++r) {
                float val = acc[f][r] + bf2f((ushort)qs[r][f]) + bf2f((ushort)qd[r][f]);
                Tsm[(rm + lg * 4 + r) * 136 + f * 16 + l16] = f2bf(gelu_fast(val));
            }
    }
    __syncthreads();

    #pragma unroll
    for (int it = 0; it < 8; ++it) {
        int r0 = it * 16 + wid * 4;
        gload16(WT2 + (size_t)(r0 + (lane >> 4)) * 128 + (lane & 15) * 8,
                &Bsm[r0 * 128]);
    }
    __syncthreads();

    // phase 2
    f4 acc2[8] = {};
    #pragma unroll
    for (int kc = 0; kc < 2; ++kc)
        #pragma unroll
        for (int ks = 0; ks < 2; ++ks) {
            int ko = kc * 64 + ks * 32 + lg * 8;
            int kos = ko ^ sx;
            bf8 a = *(const bf8*)&Tsm[(rm + l16) * 136 + ko];
            #pragma unroll
            for (int f = 0; f < 8; ++f) {
                bf8 b = *(const bf8*)&Bsm[(f * 16 + l16) * 128 + kos];
                acc2[f] = __builtin_amdgcn_mfma_f32_16x16x32_bf16(a, b, acc2[f], 0, 0, 0);
            }
        }

    // epilogue 2
    {
        float v[8][4];
        #pragma unroll
        for (int f = 0; f < 8; ++f) {
            int col = f * 16 + l16;
            float bias = loadf(be2, col, f32);
            #pragma unroll
            for (int r = 0; r < 4; ++r) {
                int row = rm + lg * 4 + r;
                v[f][r] = acc2[f][r] + bias + bf2f(Asm[row * 136 + col]);
            }
        }
        #pragma unroll
        for (int r = 0; r < 4; ++r) {
            float s = 0.f;
            #pragma unroll
            for (int f = 0; f < 8; ++f) s += v[f][r];
            s += __shfl_xor(s, 1); s += __shfl_xor(s, 2);
            s += __shfl_xor(s, 4); s += __shfl_xor(s, 8);
            float mu = s * (1.0f / 128.0f);
            float q = 0.f;
            #pragma unroll
            for (int f = 0; f < 8; ++f) { float d = v[f][r] - mu; q += d * d; }
            q += __shfl_xor(q, 1); q += __shfl_xor(q, 2);
            q += __shfl_xor(q, 4); q += __shfl_xor(q, 8);
            float rstd = rsqrtf(q * (1.0f / 128.0f) + 1e-5f);
            int row = rm + lg * 4 + r;
            #pragma unroll
            for (int f = 0; f < 8; ++f) {
                int col = f * 16 + l16;
                float y = (v[f][r] - mu) * rstd * loadf(neg, col, f32) + loadf(neb, col, f32);
                Tsm[row * 136 + col] = f2bf(y);
            }
        }
    }
    __syncthreads();

    bf4 ps[4][4], pd[4][4];
    #pragma unroll
    for (int ai = 0; ai < 4; ++ai) {
        int p0 = ai * 16 + lg * 4;
        #pragma unroll
        for (int r = 0; r < 4; ++r) {
            ps[ai][r] = *(const bf4*)&Pab[(size_t)SrcS[p0 + r] * 512 + wid * 64 + l16 * 4];
            pd[ai][r] = *(const bf4*)&Pab[(size_t)DstS[p0 + r] * 512 + 256 + wid * 64 + l16 * 4];
        }
    }

    {
        int row = tid >> 2, pc = (tid & 3) * 32;
        size_t obase = (size_t)NNODE * HIDD + (size_t)PermS[row] * ED + pc;
        #pragma unroll
        for (int q2 = 0; q2 < 4; ++q2) {
            bf8 w = *(const bf8*)&Tsm[row * 136 + pc + q2 * 8];
            if (f32) {
                f4 lo, hi;
                lo[0] = bf2f((ushort)w[0]); lo[1] = bf2f((ushort)w[1]);
                lo[2] = bf2f((ushort)w[2]); lo[3] = bf2f((ushort)w[3]);
                hi[0] = bf2f((ushort)w[4]); hi[1] = bf2f((ushort)w[5]);
                hi[2] = bf2f((ushort)w[6]); hi[3] = bf2f((ushort)w[7]);
                *(f4*)((float*)out + obase + q2 * 8) = lo;
                *(f4*)((float*)out + obase + q2 * 8 + 4) = hi;
            } else {
                *(bf8*)((ushort*)out + obase + q2 * 8) = w;
            }
        }
    }

    // phase 3
    f4 accN[4][2][2] = {};
    #pragma unroll
    for (int nh = 0; nh < 2; ++nh) {
        #pragma unroll
        for (int it = 0; it < 8; ++it) {
            int r0 = it * 16 + wid * 4;
            gload16(WvcT + (size_t)(nh * 128 + r0 + (lane >> 4)) * 128 + (lane & 15) * 8,
                    &Bsm[r0 * 128]);
        }
        __syncthreads();
        #pragma unroll
        for (int kc = 0; kc < 2; ++kc)
            #pragma unroll
            for (int ks = 0; ks < 2; ++ks) {
                int ko = kc * 64 + ks * 32 + lg * 8;
                int kos = ko ^ sx;
                bf8 a[4], b[2];
                #pragma unroll
                for (int ai = 0; ai < 4; ++ai)
                    a[ai] = *(const bf8*)&Tsm[(ai * 16 + l16) * 136 + ko];
                #pragma unroll
                for (int bi = 0; bi < 2; ++bi)
                    b[bi] = *(const bf8*)&Bsm[(wid * 32 + bi * 16 + l16) * 128 + kos];
                #pragma unroll
                for (int ai = 0; ai < 4; ++ai)
                    #pragma unroll
                    for (int bi = 0; bi < 2; ++bi)
                        accN[ai][nh][bi] = __builtin_amdgcn_mfma_f32_16x16x32_bf16(a[ai], b[bi], accN[ai][nh][bi], 0, 0, 0);
            }
        __syncthreads();
    }

    // epilogue 3
    #pragma unroll
    for (int ai = 0; ai < 4; ++ai) {
        int p0 = ai * 16 + lg * 4;
        int dd[4];
        #pragma unroll
        for (int r = 0; r < 4; ++r) dd[r] = DstS[p0 + r];
        #pragma unroll
        for (int nh = 0; nh < 2; ++nh)
            #pragma unroll
            for (int bi = 0; bi < 2; ++bi) {
                int col = nh * 128 + wid * 32 + bi * 16 + l16;
                const int j = nh * 2 + bi;
                float v0 = gelu_fast(accN[ai][nh][bi][0] + bf2f((ushort)ps[ai][0][j]) + bf2f((ushort)pd[ai][0][j]));
                float v1 = gelu_fast(accN[ai][nh][bi][1] + bf2f((ushort)ps[ai][1][j]) + bf2f((ushort)pd[ai][1][j]));
                float v2 = gelu_fast(accN[ai][nh][bi][2] + bf2f((ushort)ps[ai][2][j]) + bf2f((ushort)pd[ai][2][j]));
                float v3 = gelu_fast(accN[ai][nh][bi][3] + bf2f((ushort)ps[ai][3][j]) + bf2f((ushort)pd[ai][3][j]));
                float s = v0; int d = dd[0];
                if (dd[1] == d) s += v1; else { fadd_native(&S[(size_t)d * HIDD + col], s); d = dd[1]; s = v1; }
                if (dd[2] == d) s += v2; else { fadd_native(&S[(size_t)d * HIDD + col], s); d = dd[2]; s = v2; }
                if (dd[3] == d) s += v3; else { fadd_native(&S[(size_t)d * HIDD + col], s); d = dd[3]; s = v3; }
                fadd_native(&S[(size_t)d * HIDD + col], s);
            }
    }
}

// ---- node phase 2 + LN: 32 nodes/block, 313 blocks ----
__global__ __launch_bounds__(256) void hn_gemm_kernel(
    const float* __restrict__ S, const ushort* __restrict__ WTv2,
    const void* __restrict__ bv2, const u32* __restrict__ cnt,
    const void* __restrict__ h,
    const void* __restrict__ nvg, const void* __restrict__ nvb,
    void* __restrict__ out, const u32* __restrict__ flags)
{
    const bool f32 = flags[0] != 0;
    constexpr int LDV = 260;
    __shared__ float Vsm[32 * LDV];

    const int tid = threadIdx.x;
    const int wid = tid >> 6, lane = tid & 63;
    const int l16 = lane & 15, lg = lane >> 4;
    const int node0 = blockIdx.x * 32;
    const int n0 = wid * 64;

    size_t ra[2];
    #pragma unroll
    for (int ai = 0; ai < 2; ++ai) {
        int row = node0 + ai * 16 + l16;
        ra[ai] = (size_t)(row < NNODE ? row : NNODE - 1) * HIDD;
    }
    int bb[4];
    #pragma unroll
    for (int bi = 0; bi < 4; ++bi) bb[bi] = (n0 + bi * 16 + l16) * HIDD;

    f4 acc[2][4] = {};
    for (int kc = 0; kc < 4; ++kc) {
        #pragma unroll
        for (int ks = 0; ks < 2; ++ks) {
            int kk = kc * 64 + ks * 32 + lg * 8;
            bf8 b[4];
            #pragma unroll
            for (int bi = 0; bi < 4; ++bi) b[bi] = *(const bf8*)&WTv2[bb[bi] + kk];
            #pragma unroll
            for (int ai = 0; ai < 2; ++ai) {
                bf8 a = load8(S, ra[ai] + kk, true);
                #pragma unroll
                for (int bi = 0; bi < 4; ++bi)
                    acc[ai][bi] = __builtin_amdgcn_mfma_f32_16x16x32_bf16(a, b[bi], acc[ai][bi], 0, 0, 0);
            }
        }
    }

    #pragma unroll
    for (int bi = 0; bi < 4; ++bi) {
        int col = n0 + bi * 16 + l16;
        float b2 = loadf(bv2, col, f32);
        #pragma unroll
        for (int ai = 0; ai < 2; ++ai)
            #pragma unroll
            for (int r = 0; r < 4; ++r) {
                int rowl = ai * 16 + lg * 4 + r;
                int gr = node0 + rowl;
                int grc = gr < NNODE ? gr : NNODE - 1;
                float c = (float)cnt[grc];
                float inv = 1.0f / fmaxf(c, 1.0f);
                float val = (acc[ai][bi][r] + c * b2) * inv
                          + loadf(h, (size_t)grc * HIDD + col, f32);
                Vsm[rowl * LDV + col] = val;
            }
    }
    __syncthreads();

    if (wid < 2) {
        #pragma unroll
        for (int rr = 0; rr < 4; ++rr) {
            int rowl = wid * 16 + lg * 4 + rr;
            int gr = node0 + rowl;
            float x[16];
            #pragma unroll
            for (int f = 0; f < 16; ++f) x[f] = Vsm[rowl * LDV + f * 16 + l16];
            float s = 0.f;
            #pragma unroll
            for (int f = 0; f < 16; ++f) s += x[f];
            s += __shfl_xor(s, 1); s += __shfl_xor(s, 2);
            s += __shfl_xor(s, 4); s += __shfl_xor(s, 8);
            float mu = s * (1.0f / 256.0f);
            float q = 0.f;
            #pragma unroll
            for (int f = 0; f < 16; ++f) { float d = x[f] - mu; q += d * d; }
            q += __shfl_xor(q, 1); q += __shfl_xor(q, 2);
            q += __shfl_xor(q, 4); q += __shfl_xor(q, 8);
            float rstd = rsqrtf(q * (1.0f / 256.0f) + 1e-5f);
            if (gr < NNODE) {
                #pragma unroll
                for (int f = 0; f < 16; ++f) {
                    int col = f * 16 + l16;
                    float y = (x[f] - mu) * rstd * loadf(nvg, col, f32) + loadf(nvb, col, f32);
                    storef(out, (size_t)gr * HIDD + col, y, f32);
                }
            }
        }
    }
}

extern "C" void kernel_launch(void* const* d_in, const int* in_sizes, int n_in,
                              void* d_out, int out_size, void* d_ws, size_t ws_size,
                              hipStream_t stream)
{
    (void)in_sizes; (void)n_in; (void)out_size; (void)ws_size;
    const void* h   = d_in[0];
    const void* e   = d_in[1];
    const int*  ei  = (const int*)d_in[2];
    const void* We1 = d_in[3];
    const void* be1 = d_in[4];
    const void* We2 = d_in[5];
    const void* be2 = d_in[6];
    const void* Wv1 = d_in[7];
    const void* bv1 = d_in[8];
    const void* Wv2 = d_in[9];
    const void* bv2 = d_in[10];
    const void* neg = d_in[11];
    const void* neb = d_in[12];
    const void* nvg = d_in[13];
    const void* nvb = d_in[14];

    char* ws = (char*)d_ws;
    u32*   flags = (u32*)ws;
    float* S     = (float*)(ws + 256);
    u32*   cnt   = (u32*)(ws + 256 + (size_t)NNODE * HIDD * 4);
    size_t off = 256 + (size_t)NNODE * HIDD * 4 + ((size_t)NNODE * 4 + 255) / 256 * 256;
    int*   head = (int*)(ws + off);            off += ((size_t)NNODE * 4 + 255) / 256 * 256;
    int*   perm = (int*)(ws + off);            off += (size_t)NEDGE * 4;
    int*   dsts = (int*)(ws + off);            off += (size_t)NEDGE * 4;
    ushort* WTb  = (ushort*)(ws + off);
    ushort* WTe  = WTb;                        // [256][256]
    ushort* WT1c = WTb + 65536;                // [128][128] swizzled
    ushort* WT2  = WTb + 81920;                // [128][128] swizzled
    ushort* WTv  = WTb + 98304;                // [512][256]
    ushort* WvcT = WTb + 229376;               // [256][128] swizzled
    ushort* WTv2 = WTb + 262144;               // [256][256]
    ushort* hb   = WTb + 327680;                       // [10000][256] bf16
    ushort* Qab  = hb + (size_t)NNODE * HIDD;          // [10000][256] bf16 (permuted)
    ushort* Pab  = Qab + (size_t)NNODE * 256;          // [10000][512] bf16 (permuted)

    hipMemsetAsync(S, 0, (size_t)NNODE * HIDD * 4 + (size_t)NNODE * 4, stream);

    combo_kernel<<<PREP_B + HCONV_B + COUNT_B, 256, 0, stream>>>(
        h, ei, We1, We2, Wv1, Wv2, WTb, hb, cnt, flags);
    scan_kernel<<<1, 256, 0, stream>>>(cnt, head);
    fillqp_kernel<<<FILL_B + 2 * QPB32, 256, 0, stream>>>(
        ei, head, perm, dsts, hb, WTe, WTv, be1, bv1, Qab, Pab, flags);

    fused_kernel<<<FWG, 256, 0, stream>>>(e, ei, perm, dsts,
                                          WT1c, WT2, be2, Qab,
                                          neg, neb, WvcT, Pab,
                                          S, d_out, flags);
    hn_gemm_kernel<<<QPB32, 256, 0, stream>>>(S, WTv2, bv2, cnt, h,
                                              nvg, nvb, d_out, flags);
}